// Round 1
// baseline (2675.027 us; speedup 1.0000x reference)
//
#include <hip/hip_runtime.h>

#define HH 256
#define WW 256
#define NPIX (HH*WW)
#define LL 16
#define NL (NPIX*LL)
#define PP 136
#define PP2 (PP*2)

// constants (double-evaluated, cast to float -- matches JAX weak-typed scalars)
static constexpr float SIGMAP_F = (float)((1.0/256.0)/(3.0+16.0)); // res/(3+l)
static constexpr float TAUU_F   = (float)((1.0/256.0)/6.0);        // res/6
static constexpr float TAU_F    = (float)(1.0/36.0);               // 1/(2+136/4)

__device__ __forceinline__ float clampf(float x, float lo, float hi){
    return fminf(fmaxf(x, lo), hi);
}

// ---------------- init: u/ubar = f broadcast; px/pt/musum = 0; nrj = 0 -------
__global__ __launch_bounds__(256) void k_init(const float* __restrict__ f,
    float* __restrict__ u, float* __restrict__ ubar,
    float* __restrict__ px, float* __restrict__ pt,
    float* __restrict__ musum, float* __restrict__ nrj)
{
    int tid = blockIdx.x*256 + threadIdx.x;
    if (tid == 0) *nrj = 0.0f;
    if (tid >= NL) return;
    int n = tid >> 4;
    float fv = f[n];
    u[tid] = fv; ubar[tid] = fv;
    px[tid] = 0.0f; px[NL + tid] = 0.0f;
    pt[tid] = 0.0f;
    musum[tid] = 0.0f; musum[NL + tid] = 0.0f;
}

// ---------------- prox: dual p update (per pixel,label) ----------------------
__global__ __launch_bounds__(256) void k_prox(const float* __restrict__ f,
    const float* __restrict__ ubar,
    float* __restrict__ px, float* __restrict__ pt,
    const float* __restrict__ musum)
{
    int tid = blockIdx.x*256 + threadIdx.x;
    if (tid >= NL) return;
    int z = tid & (LL-1);
    int n = tid >> 4;
    int i = n >> 8;
    int j = n & (WW-1);

    float ub = ubar[tid];
    float g0 = (i < HH-1) ? (ubar[tid + WW*LL] - ub) * 256.0f : 0.0f;
    float g1 = (j < WW-1) ? (ubar[tid + LL]    - ub) * 256.0f : 0.0f;
    float gt = (z < LL-1) ? (ubar[tid + 1]     - ub) * 16.0f  : 0.0f;

    float ux0 = px[tid]      + SIGMAP_F * (g0 + musum[tid]);
    float ux1 = px[NL + tid] + SIGMAP_F * (g1 + musum[NL + tid]);
    float ut  = pt[tid]      + SIGMAP_F * gt;

    float klf = (float)(z + 1) * 0.0625f - f[n];
    float pen = 0.5f * klf * klf;            // lmbda = 0.5

    float n2 = ux0*ux0 + ux1*ux1;
    float B  = 0.25f * n2 - pen;
    bool mask = ut < B;

    float px0 = ux0, px1 = ux1, ptn = ut;
    if (mask) {
        float y    = ut + pen;
        float norm = sqrtf(n2);
        float a    = 0.5f * norm;
        float b    = (2.0f/3.0f) * (1.0f - 0.5f*y);
        float v;
        if (b < 0.0f) {
            float sb  = sqrtf(-b);
            float sb3 = sb*sb*sb;
            float dd  = (a - sb3)*(a + sb3);
            if (dd < 0.0f) {
                float ratio = clampf(a / sb3, -1.0f, 1.0f);
                v = 2.0f * sb * cosf(acosf(ratio) * (1.0f/3.0f));
            } else {
                float c = cbrtf(a + sqrtf(dd));
                v = (c == 0.0f) ? 0.0f : (c - b/c);
            }
        } else {
            float dd = a*a + b*b*b;          // >= 0
            float c  = cbrtf(a + sqrtf(dd));
            v = (c == 0.0f) ? 0.0f : (c - b/c);
        }
        if (norm == 0.0f) { px0 = 0.0f; px1 = 0.0f; }
        else              { float s = 2.0f*v/norm; px0 = s*ux0; px1 = s*ux1; }
        ptn = 0.25f*(px0*px0 + px1*px1) - pen;
    }
    px[tid] = px0; px[NL + tid] = px1; pt[tid] = ptn;
}

// ---------------- s & mu update (per pixel), also writes musum(mu_new) -------
// layouts: sx/mu*: [n][p][d] -> n*PP2 + p*2 + d ;  px: [d][n][z] ; musum: [d][n][z]
__global__ __launch_bounds__(256) void k_smu(const float* __restrict__ px,
    float* __restrict__ sx,
    const float* __restrict__ muCur,   // mu_t      (read)
    float* __restrict__ muOld,         // mu_{t-1}  (read) -> mu_{t+1} (write)
    float* __restrict__ musum)
{
    int n = blockIdx.x*256 + threadIdx.x;
    if (n >= NPIX) return;

    float p0[LL], p1[LL];
    #pragma unroll
    for (int q = 0; q < LL/4; ++q) {
        float4 a = reinterpret_cast<const float4*>(px + (size_t)n*LL)[q];
        float4 b = reinterpret_cast<const float4*>(px + NL + (size_t)n*LL)[q];
        p0[4*q+0]=a.x; p0[4*q+1]=a.y; p0[4*q+2]=a.z; p0[4*q+3]=a.w;
        p1[4*q+0]=b.x; p1[4*q+1]=b.y; p1[4*q+2]=b.z; p1[4*q+3]=b.w;
    }

    float RS0[LL], RS1[LL], C0[LL], C1[LL];
    #pragma unroll
    for (int q = 0; q < LL; ++q) { RS0[q]=0.f; RS1[q]=0.f; C0[q]=0.f; C1[q]=0.f; }

    size_t base = (size_t)n * PP2;
    int p = 0;
    #pragma unroll
    for (int a = 0; a < LL; ++a) {
        float t0 = 0.0f, t1 = 0.0f;
        #pragma unroll
        for (int b = a; b < LL; ++b) {
            t0 += p0[b]; t1 += p1[b];
            size_t idx = base + (size_t)p*2;
            float sx0 = sx[idx],    sx1 = sx[idx+1];
            float mC0 = muCur[idx], mC1 = muCur[idx+1];
            float mO0 = muOld[idx], mO1 = muOld[idx+1];
            // mubar = 2*muCur - muOld ; mx = sx - mubar (sigmas = 1)
            float mx0 = sx0 - (2.0f*mC0 - mO0);
            float mx1 = sx1 - (2.0f*mC1 - mO1);
            float snorm = sqrtf(mx0*mx0 + mx1*mx1);
            if (snorm > 25.6f) {          // nu*H
                float sc = 0.1f / snorm;  // nu / snorm
                mx0 *= sc; mx1 *= sc;
            }
            sx[idx] = mx0; sx[idx+1] = mx1;
            float mn0 = mC0 + TAU_F*(mx0 - t0);
            float mn1 = mC1 + TAU_F*(mx1 - t1);
            muOld[idx] = mn0; muOld[idx+1] = mn1;
            RS0[a] += mn0; RS1[a] += mn1;
            C0[b]  += mn0; C1[b]  += mn1;
            ++p;
        }
    }
    // musum[z] over combos (a<=z<=b):  ms[0]=RS[0]; ms[z+1]=ms[z]+RS[z+1]-C[z]
    float ms0 = RS0[0], ms1 = RS1[0];
    musum[(size_t)n*LL + 0]      = ms0;
    musum[NL + (size_t)n*LL + 0] = ms1;
    #pragma unroll
    for (int zq = 1; zq < LL; ++zq) {
        ms0 += RS0[zq] - C0[zq-1];
        ms1 += RS1[zq] - C1[zq-1];
        musum[(size_t)n*LL + zq]      = ms0;
        musum[NL + (size_t)n*LL + zq] = ms1;
    }
}

// ---------------- primal u update (per pixel,label) --------------------------
__global__ __launch_bounds__(256) void k_u(const float* __restrict__ px,
    const float* __restrict__ pt,
    float* __restrict__ u, float* __restrict__ ubar,
    float* __restrict__ nrj, int compute_nrj)
{
    __shared__ float wsum[4];
    int tid = blockIdx.x*256 + threadIdx.x;
    if (tid >= NL) return;
    int z = tid & (LL-1);
    int n = tid >> 4;
    int i = n >> 8;
    int j = n & (WW-1);

    float p0c = px[tid];
    float p1c = px[NL + tid];
    float d0 = ((i < HH-1) ? p0c : 0.0f) - ((i > 0) ? px[tid - WW*LL] : 0.0f);
    float d1 = ((j < WW-1) ? p1c : 0.0f) - ((j > 0) ? px[NL + tid - LL] : 0.0f);
    float ptc = pt[tid];
    float dt = ((z < LL-1) ? ptc : 0.0f) - ((z > 0) ? pt[tid - 1] : 0.0f);

    float uo = u[tid];
    float Dv = uo + TAUU_F * ((d0 + d1) * 256.0f + dt * 16.0f);
    float un = clampf(Dv, 0.0f, 1.0f);
    if (z == 0)     un = 1.0f;
    if (z == LL-1)  un = 0.0f;
    u[tid]    = un;
    ubar[tid] = 2.0f*un - uo;

    if (compute_nrj) {
        float v = fabsf(un - uo);
        #pragma unroll
        for (int off = 32; off > 0; off >>= 1) v += __shfl_down(v, off);
        int lane = threadIdx.x & 63, wv = threadIdx.x >> 6;
        if (lane == 0) wsum[wv] = v;
        __syncthreads();
        if (threadIdx.x == 0) {
            atomicAdd(nrj, wsum[0] + wsum[1] + wsum[2] + wsum[3]);
        }
    }
}

// ---------------- tail scalars ----------------------------------------------
__global__ void k_final(const float* __restrict__ nrj, float* __restrict__ out_tail)
{
    if (threadIdx.x == 0) {
        float e = *nrj;
        out_tail[0] = e;
        out_tail[1] = e * (1.0f/1048576.0f);   // nrj / (H*W*1*l)
        out_tail[2] = 0.0f;
    }
}

extern "C" void kernel_launch(void* const* d_in, const int* in_sizes, int n_in,
                              void* d_out, int out_size, void* d_ws, size_t ws_size,
                              hipStream_t stream)
{
    const float* f = (const float*)d_in[0];
    float* out = (float*)d_out;

    char* w = (char*)d_ws;
    size_t off = 0;
    auto alloc = [&](size_t nfloats) {
        float* p = (float*)(w + off);
        off += nfloats * sizeof(float);
        return p;
    };
    float* sx    = alloc((size_t)NPIX * PP2);   // 71.3 MB
    float* muA   = alloc((size_t)NPIX * PP2);   // 71.3 MB
    float* muB   = alloc((size_t)NPIX * PP2);   // 71.3 MB
    float* px    = alloc(2*(size_t)NL);         // 8.4 MB
    float* musum = alloc(2*(size_t)NL);         // 8.4 MB
    float* pt    = alloc((size_t)NL);           // 4.2 MB
    float* u     = alloc((size_t)NL);           // 4.2 MB
    float* ubar  = alloc((size_t)NL);           // 4.2 MB
    float* nrj   = alloc(64);
    (void)ws_size; (void)in_sizes; (void)n_in; (void)out_size;

    // zero big dual state (sx, muA, muB are contiguous)
    hipMemsetAsync(sx, 0, (size_t)3 * NPIX * PP2 * sizeof(float), stream);
    k_init<<<NL/256, 256, 0, stream>>>(f, u, ubar, px, pt, musum, nrj);

    float* mcur = muB;   // mu_t      (zeros initially)
    float* mold = muA;   // mu_{t-1}  (zeros initially)
    for (int it = 0; it < 10; ++it) {
        k_prox<<<NL/256, 256, 0, stream>>>(f, ubar, px, pt, musum);
        k_smu <<<NPIX/256, 256, 0, stream>>>(px, sx, mcur, mold, musum);
        { float* tmp = mcur; mcur = mold; mold = tmp; }  // mold-buffer now holds mu_{t+1}
        k_u   <<<NL/256, 256, 0, stream>>>(px, pt, u, ubar, nrj, it == 0 ? 1 : 0);
    }

    hipMemcpyAsync(out, u, (size_t)NL*sizeof(float), hipMemcpyDeviceToDevice, stream);
    k_final<<<1, 64, 0, stream>>>(nrj, out + NL);
}

// Round 2
// 874.677 us; speedup vs baseline: 3.0583x; 3.0583x over previous
//
#include <hip/hip_runtime.h>

#define HH 256
#define WW 256
#define NPIX (HH*WW)
#define LL 16
#define NL (NPIX*LL)
#define PP 136
#define PP2 (PP*2)

// constants (double-evaluated, cast to float -- matches JAX weak-typed scalars)
static constexpr float SIGMAP_F = (float)((1.0/256.0)/(3.0+16.0)); // res/(3+l)
static constexpr float TAUU_F   = (float)((1.0/256.0)/6.0);        // res/6
static constexpr float TAU_F    = (float)(1.0/36.0);               // 1/(2+136/4)

__device__ __forceinline__ float clampf(float x, float lo, float hi){
    return fminf(fmaxf(x, lo), hi);
}

// ---------------- init: u/ubar = f broadcast; px/pt/musum = 0; nrj = 0 -------
__global__ __launch_bounds__(256) void k_init(const float* __restrict__ f,
    float* __restrict__ u, float* __restrict__ ubar,
    float* __restrict__ px, float* __restrict__ pt,
    float* __restrict__ musum, float* __restrict__ nrj)
{
    int tid = blockIdx.x*256 + threadIdx.x;
    if (tid == 0) *nrj = 0.0f;
    if (tid >= NL) return;
    int n = tid >> 4;
    float fv = f[n];
    u[tid] = fv; ubar[tid] = fv;
    px[tid] = 0.0f; px[NL + tid] = 0.0f;
    pt[tid] = 0.0f;
    musum[tid] = 0.0f; musum[NL + tid] = 0.0f;
}

// ---------------- prox: dual p update (per pixel,label) ----------------------
__global__ __launch_bounds__(256) void k_prox(const float* __restrict__ f,
    const float* __restrict__ ubar,
    float* __restrict__ px, float* __restrict__ pt,
    const float* __restrict__ musum)
{
    int tid = blockIdx.x*256 + threadIdx.x;
    if (tid >= NL) return;
    int z = tid & (LL-1);
    int n = tid >> 4;
    int i = n >> 8;
    int j = n & (WW-1);

    float ub = ubar[tid];
    float g0 = (i < HH-1) ? (ubar[tid + WW*LL] - ub) * 256.0f : 0.0f;
    float g1 = (j < WW-1) ? (ubar[tid + LL]    - ub) * 256.0f : 0.0f;
    float gt = (z < LL-1) ? (ubar[tid + 1]     - ub) * 16.0f  : 0.0f;

    float ux0 = px[tid]      + SIGMAP_F * (g0 + musum[tid]);
    float ux1 = px[NL + tid] + SIGMAP_F * (g1 + musum[NL + tid]);
    float ut  = pt[tid]      + SIGMAP_F * gt;

    float klf = (float)(z + 1) * 0.0625f - f[n];
    float pen = 0.5f * klf * klf;            // lmbda = 0.5

    float n2 = ux0*ux0 + ux1*ux1;
    float B  = 0.25f * n2 - pen;
    bool mask = ut < B;

    float px0 = ux0, px1 = ux1, ptn = ut;
    if (mask) {
        float y    = ut + pen;
        float norm = sqrtf(n2);
        float a    = 0.5f * norm;
        float b    = (2.0f/3.0f) * (1.0f - 0.5f*y);
        float v;
        if (b < 0.0f) {
            float sb  = sqrtf(-b);
            float sb3 = sb*sb*sb;
            float dd  = (a - sb3)*(a + sb3);
            if (dd < 0.0f) {
                float ratio = clampf(a / sb3, -1.0f, 1.0f);
                v = 2.0f * sb * cosf(acosf(ratio) * (1.0f/3.0f));
            } else {
                float c = cbrtf(a + sqrtf(dd));
                v = (c == 0.0f) ? 0.0f : (c - b/c);
            }
        } else {
            float dd = a*a + b*b*b;          // >= 0
            float c  = cbrtf(a + sqrtf(dd));
            v = (c == 0.0f) ? 0.0f : (c - b/c);
        }
        if (norm == 0.0f) { px0 = 0.0f; px1 = 0.0f; }
        else              { float s = 2.0f*v/norm; px0 = s*ux0; px1 = s*ux1; }
        ptn = 0.25f*(px0*px0 + px1*px1) - pen;
    }
    px[tid] = px0; px[NL + tid] = px1; pt[tid] = ptn;
}

// ---------------- s & mu update: one thread per (pixel, direction) -----------
// Big-state layout (plane-major, coalesced): idx = (p*2+d)*NPIX + n
// px / musum layout: [d][n][z] -> d*NL + n*16 + z
// Lane pairing: t = blk*256+tid; d = t&1, n = t>>1 -> lanes 2k/2k+1 share n.
// The only cross-direction coupling is snorm^2 = mx0^2 + mx1^2 -> shfl_xor(1).
__global__ __launch_bounds__(256) void k_smu(const float* __restrict__ px,
    float* __restrict__ sx,
    const float* __restrict__ muCur,   // mu_t      (read)
    float* __restrict__ muOld,         // mu_{t-1}  (read) -> mu_{t+1} (write)
    float* __restrict__ musum)
{
    int t = blockIdx.x*256 + threadIdx.x;
    int d = t & 1;
    int n = t >> 1;

    float p[LL];
    {
        const float4* pxd = reinterpret_cast<const float4*>(px + (size_t)d*NL + (size_t)n*LL);
        #pragma unroll
        for (int q = 0; q < LL/4; ++q) {
            float4 a = pxd[q];
            p[4*q+0]=a.x; p[4*q+1]=a.y; p[4*q+2]=a.z; p[4*q+3]=a.w;
        }
    }

    float RS[LL], C[LL];
    #pragma unroll
    for (int q = 0; q < LL; ++q) { RS[q]=0.f; C[q]=0.f; }

    int pi = 0;
    #pragma unroll
    for (int a = 0; a < LL; ++a) {
        float tsum = 0.0f;
        #pragma unroll
        for (int b = a; b < LL; ++b) {
            tsum += p[b];
            size_t idx = (size_t)(pi*2 + d)*NPIX + n;
            float sxv = sx[idx];
            float mC  = muCur[idx];
            float mO  = muOld[idx];
            // mubar = 2*muCur - muOld ; mx = sx - mubar (sigmas = 1)
            float mx = sxv - (2.0f*mC - mO);
            float mo = __shfl_xor(mx, 1);
            float snorm = sqrtf(mx*mx + mo*mo);
            if (snorm > 25.6f) {          // nu*H
                mx *= 0.1f / snorm;       // nu / snorm
            }
            sx[idx] = mx;
            float mn = mC + TAU_F*(mx - tsum);
            muOld[idx] = mn;
            RS[a] += mn; C[b] += mn;
            ++pi;
        }
    }

    // musum[z] over combos (a<=z<=b):  ms[0]=RS[0]; ms[z+1]=ms[z]+RS[z+1]-C[z]
    float* msd = musum + (size_t)d*NL + (size_t)n*LL;
    float ms = RS[0];
    msd[0] = ms;
    #pragma unroll
    for (int zq = 1; zq < LL; ++zq) {
        ms += RS[zq] - C[zq-1];
        msd[zq] = ms;
    }
}

// ---------------- primal u update (per pixel,label) --------------------------
__global__ __launch_bounds__(256) void k_u(const float* __restrict__ px,
    const float* __restrict__ pt,
    float* __restrict__ u, float* __restrict__ ubar,
    float* __restrict__ nrj, int compute_nrj)
{
    __shared__ float wsum[4];
    int tid = blockIdx.x*256 + threadIdx.x;
    if (tid >= NL) return;
    int z = tid & (LL-1);
    int n = tid >> 4;
    int i = n >> 8;
    int j = n & (WW-1);

    float p0c = px[tid];
    float p1c = px[NL + tid];
    float d0 = ((i < HH-1) ? p0c : 0.0f) - ((i > 0) ? px[tid - WW*LL] : 0.0f);
    float d1 = ((j < WW-1) ? p1c : 0.0f) - ((j > 0) ? px[NL + tid - LL] : 0.0f);
    float ptc = pt[tid];
    float dt = ((z < LL-1) ? ptc : 0.0f) - ((z > 0) ? pt[tid - 1] : 0.0f);

    float uo = u[tid];
    float Dv = uo + TAUU_F * ((d0 + d1) * 256.0f + dt * 16.0f);
    float un = clampf(Dv, 0.0f, 1.0f);
    if (z == 0)     un = 1.0f;
    if (z == LL-1)  un = 0.0f;
    u[tid]    = un;
    ubar[tid] = 2.0f*un - uo;

    if (compute_nrj) {
        float v = fabsf(un - uo);
        #pragma unroll
        for (int off = 32; off > 0; off >>= 1) v += __shfl_down(v, off);
        int lane = threadIdx.x & 63, wv = threadIdx.x >> 6;
        if (lane == 0) wsum[wv] = v;
        __syncthreads();
        if (threadIdx.x == 0) {
            atomicAdd(nrj, wsum[0] + wsum[1] + wsum[2] + wsum[3]);
        }
    }
}

// ---------------- tail scalars ----------------------------------------------
__global__ void k_final(const float* __restrict__ nrj, float* __restrict__ out_tail)
{
    if (threadIdx.x == 0) {
        float e = *nrj;
        out_tail[0] = e;
        out_tail[1] = e * (1.0f/1048576.0f);   // nrj / (H*W*1*l)
        out_tail[2] = 0.0f;
    }
}

extern "C" void kernel_launch(void* const* d_in, const int* in_sizes, int n_in,
                              void* d_out, int out_size, void* d_ws, size_t ws_size,
                              hipStream_t stream)
{
    const float* f = (const float*)d_in[0];
    float* out = (float*)d_out;

    char* w = (char*)d_ws;
    size_t off = 0;
    auto alloc = [&](size_t nfloats) {
        float* p = (float*)(w + off);
        off += nfloats * sizeof(float);
        return p;
    };
    float* sx    = alloc((size_t)NPIX * PP2);   // 71.3 MB  [plane-major]
    float* muA   = alloc((size_t)NPIX * PP2);   // 71.3 MB  [plane-major]
    float* muB   = alloc((size_t)NPIX * PP2);   // 71.3 MB  [plane-major]
    float* px    = alloc(2*(size_t)NL);         // 8.4 MB
    float* musum = alloc(2*(size_t)NL);         // 8.4 MB
    float* pt    = alloc((size_t)NL);           // 4.2 MB
    float* u     = alloc((size_t)NL);           // 4.2 MB
    float* ubar  = alloc((size_t)NL);           // 4.2 MB
    float* nrj   = alloc(64);
    (void)ws_size; (void)in_sizes; (void)n_in; (void)out_size;

    // zero big dual state (sx, muA, muB are contiguous)
    hipMemsetAsync(sx, 0, (size_t)3 * NPIX * PP2 * sizeof(float), stream);
    k_init<<<NL/256, 256, 0, stream>>>(f, u, ubar, px, pt, musum, nrj);

    float* mcur = muB;   // mu_t      (zeros initially)
    float* mold = muA;   // mu_{t-1}  (zeros initially)
    for (int it = 0; it < 10; ++it) {
        k_prox<<<NL/256, 256, 0, stream>>>(f, ubar, px, pt, musum);
        k_smu <<<2*NPIX/256, 256, 0, stream>>>(px, sx, mcur, mold, musum);
        { float* tmp = mcur; mcur = mold; mold = tmp; }  // mold-buffer now holds mu_{t+1}
        k_u   <<<NL/256, 256, 0, stream>>>(px, pt, u, ubar, nrj, it == 0 ? 1 : 0);
    }

    hipMemcpyAsync(out, u, (size_t)NL*sizeof(float), hipMemcpyDeviceToDevice, stream);
    k_final<<<1, 64, 0, stream>>>(nrj, out + NL);
}

// Round 3
// 705.422 us; speedup vs baseline: 3.7921x; 1.2399x over previous
//
#include <hip/hip_runtime.h>

#define HH 256
#define WW 256
#define NPIX (HH*WW)
#define LL 16
#define NL (NPIX*LL)
#define PP 136
#define PP2 (PP*2)

typedef _Float16 half_t;

// constants (double-evaluated, cast to float -- matches JAX weak-typed scalars)
static constexpr float SIGMAP_F = (float)((1.0/256.0)/(3.0+16.0)); // res/(3+l)
static constexpr float TAUU_F   = (float)((1.0/256.0)/6.0);        // res/6
static constexpr float TAU_F    = (float)(1.0/36.0);               // 1/(2+136/4)

__device__ __forceinline__ float clampf(float x, float lo, float hi){
    return fminf(fmaxf(x, lo), hi);
}

// ---------------- init: u/ubar = f broadcast; px/pt/musum = 0; nrj = 0 -------
__global__ __launch_bounds__(256) void k_init(const float* __restrict__ f,
    float* __restrict__ u, float* __restrict__ ubar,
    float* __restrict__ px, float* __restrict__ pt,
    float* __restrict__ msA, float* __restrict__ msB, float* __restrict__ nrj)
{
    int tid = blockIdx.x*256 + threadIdx.x;
    if (tid == 0) *nrj = 0.0f;
    if (tid >= NL) return;
    int n = tid >> 4;
    float fv = f[n];
    u[tid] = fv; ubar[tid] = fv;
    px[tid] = 0.0f; px[NL + tid] = 0.0f;
    pt[tid] = 0.0f;
    msA[tid] = 0.0f; msA[NL + tid] = 0.0f;
    msB[tid] = 0.0f; msB[NL + tid] = 0.0f;
}

// ---------------- prox: dual p update (per pixel,label) ----------------------
__global__ __launch_bounds__(256) void k_prox(const float* __restrict__ f,
    const float* __restrict__ ubar,
    float* __restrict__ px, float* __restrict__ pt,
    const float* __restrict__ msA, const float* __restrict__ msB)
{
    int tid = blockIdx.x*256 + threadIdx.x;
    if (tid >= NL) return;
    int z = tid & (LL-1);
    int n = tid >> 4;
    int i = n >> 8;
    int j = n & (WW-1);

    float ub = ubar[tid];
    float g0 = (i < HH-1) ? (ubar[tid + WW*LL] - ub) * 256.0f : 0.0f;
    float g1 = (j < WW-1) ? (ubar[tid + LL]    - ub) * 256.0f : 0.0f;
    float gt = (z < LL-1) ? (ubar[tid + 1]     - ub) * 16.0f  : 0.0f;

    float ms0 = msA[tid]      + msB[tid];
    float ms1 = msA[NL + tid] + msB[NL + tid];
    float ux0 = px[tid]      + SIGMAP_F * (g0 + ms0);
    float ux1 = px[NL + tid] + SIGMAP_F * (g1 + ms1);
    float ut  = pt[tid]      + SIGMAP_F * gt;

    float klf = (float)(z + 1) * 0.0625f - f[n];
    float pen = 0.5f * klf * klf;            // lmbda = 0.5

    float n2 = ux0*ux0 + ux1*ux1;
    float B  = 0.25f * n2 - pen;
    bool mask = ut < B;

    float px0 = ux0, px1 = ux1, ptn = ut;
    if (mask) {
        float y    = ut + pen;
        float norm = sqrtf(n2);
        float a    = 0.5f * norm;
        float b    = (2.0f/3.0f) * (1.0f - 0.5f*y);
        float v;
        if (b < 0.0f) {
            float sb  = sqrtf(-b);
            float sb3 = sb*sb*sb;
            float dd  = (a - sb3)*(a + sb3);
            if (dd < 0.0f) {
                float ratio = clampf(a / sb3, -1.0f, 1.0f);
                v = 2.0f * sb * cosf(acosf(ratio) * (1.0f/3.0f));
            } else {
                float c = cbrtf(a + sqrtf(dd));
                v = (c == 0.0f) ? 0.0f : (c - b/c);
            }
        } else {
            float dd = a*a + b*b*b;          // >= 0
            float c  = cbrtf(a + sqrtf(dd));
            v = (c == 0.0f) ? 0.0f : (c - b/c);
        }
        if (norm == 0.0f) { px0 = 0.0f; px1 = 0.0f; }
        else              { float s = 2.0f*v/norm; px0 = s*ux0; px1 = s*ux1; }
        ptn = 0.25f*(px0*px0 + px1*px1) - pen;
    }
    px[tid] = px0; px[NL + tid] = px1; pt[tid] = ptn;
}

// ---------------- s & mu update --------------------------------------------
// Big-state (fp16, plane-major): idx = (p*2+d)*NPIX + n
// px / musum layout: [d][n][z] -> d*NL + n*16 + z
// Thread mapping: t = blk*256+tid; d = t&1, n = (t>>1)&(NPIX-1), h = t>>17.
// h=0 handles rows {0,15,1,14,2,13,3,12}; h=1 rows {4,11,5,10,6,9,7,8}
// (68 combos each, perfectly balanced; all indices compile-time static).
// Each half emits a PARTIAL musum (RS/C recurrence is valid on row subsets);
// k_prox sums the two buffers. snorm couples d=0/1 -> __shfl_xor(1) on
// adjacent lanes (same n, both h and block-uniform).
template<int A>
__device__ __forceinline__ void do_row(int d, int n, const float* __restrict__ p,
    half_t* __restrict__ sx, const half_t* __restrict__ muCur,
    half_t* __restrict__ muOld, float* __restrict__ RS, float* __restrict__ C)
{
    float tsum = 0.0f;
    float rs = 0.0f;
    #pragma unroll
    for (int b = A; b < LL; ++b) {
        tsum += p[b];
        constexpr int row_base = A*LL - (A*(A-1))/2;
        int pi = row_base + (b - A);
        size_t idx = (size_t)(pi*2 + d)*NPIX + n;
        float sxv = (float)sx[idx];
        float mC  = (float)muCur[idx];
        float mO  = (float)muOld[idx];
        // mubar = 2*muCur - muOld ; mx = sx - mubar (sigmas = 1)
        float mx = sxv - (2.0f*mC - mO);
        float mo = __shfl_xor(mx, 1);
        float snorm = sqrtf(mx*mx + mo*mo);
        if (snorm > 25.6f) {          // nu*H
            mx *= 0.1f / snorm;       // nu / snorm
        }
        sx[idx] = (half_t)mx;
        float mn = mC + TAU_F*(mx - tsum);
        muOld[idx] = (half_t)mn;
        rs += mn;
        C[b] += mn;
    }
    RS[A] = rs;
}

__global__ __launch_bounds__(256) void k_smu(const float* __restrict__ px,
    half_t* __restrict__ sx,
    const half_t* __restrict__ muCur,   // mu_t      (read)
    half_t* __restrict__ muOld,         // mu_{t-1}  (read) -> mu_{t+1} (write)
    float* __restrict__ msA,            // partial musum, h=0
    float* __restrict__ msB)            // partial musum, h=1
{
    int t = blockIdx.x*256 + threadIdx.x;
    int d = t & 1;
    int n = (t >> 1) & (NPIX-1);
    int h = t >> 17;   // wave-uniform (uniform per block, 512 blocks per h)

    float p[LL];
    {
        const float4* pxd = reinterpret_cast<const float4*>(px + (size_t)d*NL + (size_t)n*LL);
        #pragma unroll
        for (int q = 0; q < LL/4; ++q) {
            float4 a = pxd[q];
            p[4*q+0]=a.x; p[4*q+1]=a.y; p[4*q+2]=a.z; p[4*q+3]=a.w;
        }
    }

    float RS[LL], C[LL];
    #pragma unroll
    for (int q = 0; q < LL; ++q) { RS[q]=0.f; C[q]=0.f; }

    float* ms;
    if (h == 0) {
        do_row< 0>(d,n,p,sx,muCur,muOld,RS,C);
        do_row<15>(d,n,p,sx,muCur,muOld,RS,C);
        do_row< 1>(d,n,p,sx,muCur,muOld,RS,C);
        do_row<14>(d,n,p,sx,muCur,muOld,RS,C);
        do_row< 2>(d,n,p,sx,muCur,muOld,RS,C);
        do_row<13>(d,n,p,sx,muCur,muOld,RS,C);
        do_row< 3>(d,n,p,sx,muCur,muOld,RS,C);
        do_row<12>(d,n,p,sx,muCur,muOld,RS,C);
        ms = msA;
    } else {
        do_row< 4>(d,n,p,sx,muCur,muOld,RS,C);
        do_row<11>(d,n,p,sx,muCur,muOld,RS,C);
        do_row< 5>(d,n,p,sx,muCur,muOld,RS,C);
        do_row<10>(d,n,p,sx,muCur,muOld,RS,C);
        do_row< 6>(d,n,p,sx,muCur,muOld,RS,C);
        do_row< 9>(d,n,p,sx,muCur,muOld,RS,C);
        do_row< 7>(d,n,p,sx,muCur,muOld,RS,C);
        do_row< 8>(d,n,p,sx,muCur,muOld,RS,C);
        ms = msB;
    }

    // partial musum over this row-subset:
    // ms[0]=RS[0]; ms[z+1]=ms[z]+RS[z+1]-C[z]   (RS zero for rows not in set)
    float* msd = ms + (size_t)d*NL + (size_t)n*LL;
    float m = RS[0];
    msd[0] = m;
    #pragma unroll
    for (int zq = 1; zq < LL; ++zq) {
        m += RS[zq] - C[zq-1];
        msd[zq] = m;
    }
}

// ---------------- primal u update (per pixel,label) --------------------------
__global__ __launch_bounds__(256) void k_u(const float* __restrict__ px,
    const float* __restrict__ pt,
    float* __restrict__ u, float* __restrict__ ubar,
    float* __restrict__ nrj, int compute_nrj)
{
    __shared__ float wsum[4];
    int tid = blockIdx.x*256 + threadIdx.x;
    if (tid >= NL) return;
    int z = tid & (LL-1);
    int n = tid >> 4;
    int i = n >> 8;
    int j = n & (WW-1);

    float p0c = px[tid];
    float p1c = px[NL + tid];
    float d0 = ((i < HH-1) ? p0c : 0.0f) - ((i > 0) ? px[tid - WW*LL] : 0.0f);
    float d1 = ((j < WW-1) ? p1c : 0.0f) - ((j > 0) ? px[NL + tid - LL] : 0.0f);
    float ptc = pt[tid];
    float dt = ((z < LL-1) ? ptc : 0.0f) - ((z > 0) ? pt[tid - 1] : 0.0f);

    float uo = u[tid];
    float Dv = uo + TAUU_F * ((d0 + d1) * 256.0f + dt * 16.0f);
    float un = clampf(Dv, 0.0f, 1.0f);
    if (z == 0)     un = 1.0f;
    if (z == LL-1)  un = 0.0f;
    u[tid]    = un;
    ubar[tid] = 2.0f*un - uo;

    if (compute_nrj) {
        float v = fabsf(un - uo);
        #pragma unroll
        for (int off = 32; off > 0; off >>= 1) v += __shfl_down(v, off);
        int lane = threadIdx.x & 63, wv = threadIdx.x >> 6;
        if (lane == 0) wsum[wv] = v;
        __syncthreads();
        if (threadIdx.x == 0) {
            atomicAdd(nrj, wsum[0] + wsum[1] + wsum[2] + wsum[3]);
        }
    }
}

// ---------------- tail scalars ----------------------------------------------
__global__ void k_final(const float* __restrict__ nrj, float* __restrict__ out_tail)
{
    if (threadIdx.x == 0) {
        float e = *nrj;
        out_tail[0] = e;
        out_tail[1] = e * (1.0f/1048576.0f);   // nrj / (H*W*1*l)
        out_tail[2] = 0.0f;
    }
}

extern "C" void kernel_launch(void* const* d_in, const int* in_sizes, int n_in,
                              void* d_out, int out_size, void* d_ws, size_t ws_size,
                              hipStream_t stream)
{
    const float* f = (const float*)d_in[0];
    float* out = (float*)d_out;

    char* w = (char*)d_ws;
    size_t off = 0;
    auto allocf = [&](size_t nfloats) {
        float* p = (float*)(w + off);
        off += nfloats * sizeof(float);
        return p;
    };
    auto alloch = [&](size_t nhalf) {
        half_t* p = (half_t*)(w + off);
        off += nhalf * sizeof(half_t);
        return p;
    };
    half_t* sx    = alloch((size_t)NPIX * PP2);   // 35.7 MB  [plane-major fp16]
    half_t* muA   = alloch((size_t)NPIX * PP2);   // 35.7 MB
    half_t* muB   = alloch((size_t)NPIX * PP2);   // 35.7 MB
    float*  px    = allocf(2*(size_t)NL);         // 8.4 MB
    float*  msA   = allocf(2*(size_t)NL);         // 8.4 MB (partial musum h=0)
    float*  msB   = allocf(2*(size_t)NL);         // 8.4 MB (partial musum h=1)
    float*  pt    = allocf((size_t)NL);           // 4.2 MB
    float*  u     = allocf((size_t)NL);           // 4.2 MB
    float*  ubar  = allocf((size_t)NL);           // 4.2 MB
    float*  nrj   = allocf(64);
    (void)ws_size; (void)in_sizes; (void)n_in; (void)out_size;

    // zero big dual state (sx, muA, muB contiguous; fp16 zero = 0x0000)
    hipMemsetAsync(sx, 0, (size_t)3 * NPIX * PP2 * sizeof(half_t), stream);
    k_init<<<NL/256, 256, 0, stream>>>(f, u, ubar, px, pt, msA, msB, nrj);

    half_t* mcur = muB;   // mu_t      (zeros initially)
    half_t* mold = muA;   // mu_{t-1}  (zeros initially)
    for (int it = 0; it < 10; ++it) {
        k_prox<<<NL/256, 256, 0, stream>>>(f, ubar, px, pt, msA, msB);
        k_smu <<<4*NPIX/256, 256, 0, stream>>>(px, sx, mcur, mold, msA, msB);
        { half_t* tmp = mcur; mcur = mold; mold = tmp; }  // mold now holds mu_{t+1}
        k_u   <<<NL/256, 256, 0, stream>>>(px, pt, u, ubar, nrj, it == 0 ? 1 : 0);
    }

    hipMemcpyAsync(out, u, (size_t)NL*sizeof(float), hipMemcpyDeviceToDevice, stream);
    k_final<<<1, 64, 0, stream>>>(nrj, out + NL);
}

// Round 4
// 664.705 us; speedup vs baseline: 4.0244x; 1.0613x over previous
//
#include <hip/hip_runtime.h>

#define HH 256
#define WW 256
#define NPIX (HH*WW)
#define LL 16
#define NL (NPIX*LL)
#define PP 136
#define PP2 (PP*2)

typedef _Float16 half_t;

// constants (double-evaluated, cast to float -- matches JAX weak-typed scalars)
static constexpr float SIGMAP_F = (float)((1.0/256.0)/(3.0+16.0)); // res/(3+l)
static constexpr float TAUU_F   = (float)((1.0/256.0)/6.0);        // res/6
static constexpr float TAU_F    = (float)(1.0/36.0);               // 1/(2+136/4)

__device__ __forceinline__ float clampf(float x, float lo, float hi){
    return fminf(fmaxf(x, lo), hi);
}

// ---------------- init: u/ubar = f broadcast; px/pt = 0; nrj = 0 -------------
__global__ __launch_bounds__(256) void k_init(const float* __restrict__ f,
    float* __restrict__ u, float* __restrict__ ubar,
    float* __restrict__ px, float* __restrict__ pt, float* __restrict__ nrj)
{
    int tid = blockIdx.x*256 + threadIdx.x;
    if (tid == 0) *nrj = 0.0f;
    if (tid >= NL) return;
    int n = tid >> 4;
    float fv = f[n];
    u[tid] = fv; ubar[tid] = fv;
    px[tid] = 0.0f; px[NL + tid] = 0.0f;
    pt[tid] = 0.0f;
}

// ---------------- prox: dual p update (per pixel,label) ----------------------
__global__ __launch_bounds__(256) void k_prox(const float* __restrict__ f,
    const float* __restrict__ ubar,
    float* __restrict__ px, float* __restrict__ pt,
    const half_t* __restrict__ msA, const half_t* __restrict__ msB,
    const half_t* __restrict__ msC, const half_t* __restrict__ msD)
{
    int tid = blockIdx.x*256 + threadIdx.x;
    if (tid >= NL) return;
    int z = tid & (LL-1);
    int n = tid >> 4;
    int i = n >> 8;
    int j = n & (WW-1);

    float ub = ubar[tid];
    float g0 = (i < HH-1) ? (ubar[tid + WW*LL] - ub) * 256.0f : 0.0f;
    float g1 = (j < WW-1) ? (ubar[tid + LL]    - ub) * 256.0f : 0.0f;
    float gt = (z < LL-1) ? (ubar[tid + 1]     - ub) * 16.0f  : 0.0f;

    float ms0 = (float)msA[tid] + (float)msB[tid]
              + (float)msC[tid] + (float)msD[tid];
    float ms1 = (float)msA[NL + tid] + (float)msB[NL + tid]
              + (float)msC[NL + tid] + (float)msD[NL + tid];
    float ux0 = px[tid]      + SIGMAP_F * (g0 + ms0);
    float ux1 = px[NL + tid] + SIGMAP_F * (g1 + ms1);
    float ut  = pt[tid]      + SIGMAP_F * gt;

    float klf = (float)(z + 1) * 0.0625f - f[n];
    float pen = 0.5f * klf * klf;            // lmbda = 0.5

    float n2 = ux0*ux0 + ux1*ux1;
    float B  = 0.25f * n2 - pen;
    bool mask = ut < B;

    float px0 = ux0, px1 = ux1, ptn = ut;
    if (mask) {
        float y    = ut + pen;
        float norm = sqrtf(n2);
        float a    = 0.5f * norm;
        float b    = (2.0f/3.0f) * (1.0f - 0.5f*y);
        float v;
        if (b < 0.0f) {
            float sb  = sqrtf(-b);
            float sb3 = sb*sb*sb;
            float dd  = (a - sb3)*(a + sb3);
            if (dd < 0.0f) {
                float ratio = clampf(a / sb3, -1.0f, 1.0f);
                v = 2.0f * sb * cosf(acosf(ratio) * (1.0f/3.0f));
            } else {
                float c = cbrtf(a + sqrtf(dd));
                v = (c == 0.0f) ? 0.0f : (c - b/c);
            }
        } else {
            float dd = a*a + b*b*b;          // >= 0
            float c  = cbrtf(a + sqrtf(dd));
            v = (c == 0.0f) ? 0.0f : (c - b/c);
        }
        if (norm == 0.0f) { px0 = 0.0f; px1 = 0.0f; }
        else              { float s = 2.0f*v/norm; px0 = s*ux0; px1 = s*ux1; }
        ptn = 0.25f*(px0*px0 + px1*px1) - pen;
    }
    px[tid] = px0; px[NL + tid] = px1; pt[tid] = ptn;
}

// ---------------- fused s/mu update + primal u update ------------------------
// Phase A (smu): big-state (fp16, plane-major): idx = (p*2+d)*NPIX + n
//   Thread map: t = blk*256+tid in [0, 2^19); d=t&1, n=(t>>1)&(NPIX-1), h=t>>17.
//   h in {0..3} handles balanced row sets (34 combos each, all static indices):
//   {0,15,2,13} {1,14,3,12} {4,11,6,9} {5,10,7,8}. Each emits a PARTIAL fp16
//   musum (the RS/C recurrence is linear over row subsets); prox sums all 4.
//   snorm couples d=0/1 -> __shfl_xor(1) (lane pairs share n,h).
// Phase B (u-update): independent of phase A (depends only on prox outputs) --
//   no sync needed. Each thread does 2 consecutive z of one pixel via float2.
template<int A>
__device__ __forceinline__ void do_row(int d, int n, const float* __restrict__ p,
    half_t* __restrict__ sx, const half_t* __restrict__ muCur,
    half_t* __restrict__ muOld, float* __restrict__ RS, float* __restrict__ C)
{
    float tsum = 0.0f;
    float rs = 0.0f;
    #pragma unroll
    for (int b = A; b < LL; ++b) {
        tsum += p[b];
        constexpr int row_base = A*LL - (A*(A-1))/2;
        int pi = row_base + (b - A);
        size_t idx = (size_t)(pi*2 + d)*NPIX + n;
        float sxv = (float)sx[idx];
        float mC  = (float)muCur[idx];
        float mO  = (float)muOld[idx];
        // mubar = 2*muCur - muOld ; mx = sx - mubar (sigmas = 1)
        float mx = sxv - (2.0f*mC - mO);
        float mo = __shfl_xor(mx, 1);
        float snorm = sqrtf(mx*mx + mo*mo);
        if (snorm > 25.6f) {          // nu*H
            mx *= 0.1f / snorm;       // nu / snorm
        }
        sx[idx] = (half_t)mx;
        float mn = mC + TAU_F*(mx - tsum);
        muOld[idx] = (half_t)mn;
        rs += mn;
        C[b] += mn;
    }
    RS[A] = rs;
}

__global__ __launch_bounds__(256) void k_smu_u(const float* __restrict__ px,
    const float* __restrict__ pt,
    half_t* __restrict__ sx,
    const half_t* __restrict__ muCur,   // mu_t      (read)
    half_t* __restrict__ muOld,         // mu_{t-1}  (read) -> mu_{t+1} (write)
    half_t* __restrict__ msA, half_t* __restrict__ msB,
    half_t* __restrict__ msC, half_t* __restrict__ msD,
    float* __restrict__ u, float* __restrict__ ubar,
    float* __restrict__ nrj, int compute_nrj)
{
    __shared__ float wsum[4];
    int t = blockIdx.x*256 + threadIdx.x;
    int d = t & 1;
    int n = (t >> 1) & (NPIX-1);
    int h = t >> 17;   // block-uniform (512 blocks per h)

    // ---------------- phase A: s & mu ----------------
    float p[LL];
    {
        const float4* pxd = reinterpret_cast<const float4*>(px + (size_t)d*NL + (size_t)n*LL);
        #pragma unroll
        for (int q = 0; q < LL/4; ++q) {
            float4 a = pxd[q];
            p[4*q+0]=a.x; p[4*q+1]=a.y; p[4*q+2]=a.z; p[4*q+3]=a.w;
        }
    }

    float RS[LL], C[LL];
    #pragma unroll
    for (int q = 0; q < LL; ++q) { RS[q]=0.f; C[q]=0.f; }

    half_t* ms;
    if (h == 0) {
        do_row< 0>(d,n,p,sx,muCur,muOld,RS,C);
        do_row<15>(d,n,p,sx,muCur,muOld,RS,C);
        do_row< 2>(d,n,p,sx,muCur,muOld,RS,C);
        do_row<13>(d,n,p,sx,muCur,muOld,RS,C);
        ms = msA;
    } else if (h == 1) {
        do_row< 1>(d,n,p,sx,muCur,muOld,RS,C);
        do_row<14>(d,n,p,sx,muCur,muOld,RS,C);
        do_row< 3>(d,n,p,sx,muCur,muOld,RS,C);
        do_row<12>(d,n,p,sx,muCur,muOld,RS,C);
        ms = msB;
    } else if (h == 2) {
        do_row< 4>(d,n,p,sx,muCur,muOld,RS,C);
        do_row<11>(d,n,p,sx,muCur,muOld,RS,C);
        do_row< 6>(d,n,p,sx,muCur,muOld,RS,C);
        do_row< 9>(d,n,p,sx,muCur,muOld,RS,C);
        ms = msC;
    } else {
        do_row< 5>(d,n,p,sx,muCur,muOld,RS,C);
        do_row<10>(d,n,p,sx,muCur,muOld,RS,C);
        do_row< 7>(d,n,p,sx,muCur,muOld,RS,C);
        do_row< 8>(d,n,p,sx,muCur,muOld,RS,C);
        ms = msD;
    }

    // partial musum over this row-subset:
    // ms[0]=RS[0]; ms[z+1]=ms[z]+RS[z+1]-C[z]   (RS zero for rows not in set)
    {
        half_t* msd = ms + (size_t)d*NL + (size_t)n*LL;
        float m = RS[0];
        msd[0] = (half_t)m;
        #pragma unroll
        for (int zq = 1; zq < LL; ++zq) {
            m += RS[zq] - C[zq-1];
            msd[zq] = (half_t)m;
        }
    }

    // ---------------- phase B: primal u update (2 z per thread) --------------
    {
        int n2 = t >> 3;
        int z0 = (t & 7) << 1;
        int i2 = n2 >> 8;
        int j2 = n2 & (WW-1);
        size_t base = (size_t)n2*LL + z0;

        const float2 zz = make_float2(0.0f, 0.0f);
        float2 p0c = *reinterpret_cast<const float2*>(px + base);
        float2 p0u = (i2 > 0) ? *reinterpret_cast<const float2*>(px + base - (size_t)WW*LL) : zz;
        float2 p1c = *reinterpret_cast<const float2*>(px + NL + base);
        float2 p1l = (j2 > 0) ? *reinterpret_cast<const float2*>(px + NL + base - LL) : zz;
        float2 ptc = *reinterpret_cast<const float2*>(pt + base);
        float  ptm = (z0 > 0) ? pt[base - 1] : 0.0f;
        float2 uo  = *reinterpret_cast<const float2*>(u + base);

        bool iok = (i2 < HH-1), jok = (j2 < WW-1);
        float un[2], uov[2];
        uov[0] = uo.x; uov[1] = uo.y;
        float pcc[2] = {p0c.x, p0c.y}, puu[2] = {p0u.x, p0u.y};
        float qcc[2] = {p1c.x, p1c.y}, qll[2] = {p1l.x, p1l.y};
        float ptv[2] = {ptc.x, ptc.y};
        float ptprev[2] = {ptm, ptc.x};

        #pragma unroll
        for (int e = 0; e < 2; ++e) {
            int z = z0 + e;
            float d0 = (iok ? pcc[e] : 0.0f) - ((i2 > 0) ? puu[e] : 0.0f);
            float d1 = (jok ? qcc[e] : 0.0f) - ((j2 > 0) ? qll[e] : 0.0f);
            float dt = ((z < LL-1) ? ptv[e] : 0.0f) - ((z > 0) ? ptprev[e] : 0.0f);
            float Dv = uov[e] + TAUU_F * ((d0 + d1) * 256.0f + dt * 16.0f);
            float v  = clampf(Dv, 0.0f, 1.0f);
            if (z == 0)     v = 1.0f;
            if (z == LL-1)  v = 0.0f;
            un[e] = v;
        }
        float2 unw = make_float2(un[0], un[1]);
        float2 ubw = make_float2(2.0f*un[0] - uov[0], 2.0f*un[1] - uov[1]);
        *reinterpret_cast<float2*>(u + base)    = unw;
        *reinterpret_cast<float2*>(ubar + base) = ubw;

        if (compute_nrj) {
            float v = fabsf(un[0] - uov[0]) + fabsf(un[1] - uov[1]);
            #pragma unroll
            for (int off = 32; off > 0; off >>= 1) v += __shfl_down(v, off);
            int lane = threadIdx.x & 63, wv = threadIdx.x >> 6;
            if (lane == 0) wsum[wv] = v;
            __syncthreads();
            if (threadIdx.x == 0) {
                atomicAdd(nrj, wsum[0] + wsum[1] + wsum[2] + wsum[3]);
            }
        }
    }
}

// ---------------- tail scalars ----------------------------------------------
__global__ void k_final(const float* __restrict__ nrj, float* __restrict__ out_tail)
{
    if (threadIdx.x == 0) {
        float e = *nrj;
        out_tail[0] = e;
        out_tail[1] = e * (1.0f/1048576.0f);   // nrj / (H*W*1*l)
        out_tail[2] = 0.0f;
    }
}

extern "C" void kernel_launch(void* const* d_in, const int* in_sizes, int n_in,
                              void* d_out, int out_size, void* d_ws, size_t ws_size,
                              hipStream_t stream)
{
    const float* f = (const float*)d_in[0];
    float* out = (float*)d_out;

    char* w = (char*)d_ws;
    size_t off = 0;
    auto allocf = [&](size_t nfloats) {
        float* p = (float*)(w + off);
        off += nfloats * sizeof(float);
        return p;
    };
    auto alloch = [&](size_t nhalf) {
        half_t* p = (half_t*)(w + off);
        off += nhalf * sizeof(half_t);
        return p;
    };
    // fp16 block (memset together): sx, muA, muB, 4 musum partials
    half_t* sx    = alloch((size_t)NPIX * PP2);   // 35.7 MB [plane-major fp16]
    half_t* muA   = alloch((size_t)NPIX * PP2);   // 35.7 MB
    half_t* muB   = alloch((size_t)NPIX * PP2);   // 35.7 MB
    half_t* msA   = alloch(2*(size_t)NL);         // 4.2 MB
    half_t* msB   = alloch(2*(size_t)NL);         // 4.2 MB
    half_t* msC   = alloch(2*(size_t)NL);         // 4.2 MB
    half_t* msD   = alloch(2*(size_t)NL);         // 4.2 MB
    size_t half_bytes = off;
    float*  px    = allocf(2*(size_t)NL);         // 8.4 MB
    float*  pt    = allocf((size_t)NL);           // 4.2 MB
    float*  u     = allocf((size_t)NL);           // 4.2 MB
    float*  ubar  = allocf((size_t)NL);           // 4.2 MB
    float*  nrj   = allocf(64);
    (void)ws_size; (void)in_sizes; (void)n_in; (void)out_size;

    hipMemsetAsync(sx, 0, half_bytes, stream);
    k_init<<<NL/256, 256, 0, stream>>>(f, u, ubar, px, pt, nrj);

    half_t* mcur = muB;   // mu_t      (zeros initially)
    half_t* mold = muA;   // mu_{t-1}  (zeros initially)
    for (int it = 0; it < 10; ++it) {
        k_prox<<<NL/256, 256, 0, stream>>>(f, ubar, px, pt, msA, msB, msC, msD);
        k_smu_u<<<8*NPIX/256, 256, 0, stream>>>(px, pt, sx, mcur, mold,
                                                msA, msB, msC, msD,
                                                u, ubar, nrj, it == 0 ? 1 : 0);
        { half_t* tmp = mcur; mcur = mold; mold = tmp; }  // mold now holds mu_{t+1}
        // NOTE: phase B (u-update) depends only on prox outputs (px/pt), not on
        // phase A's writes -- safe to fuse without any intra-kernel sync.
    }

    hipMemcpyAsync(out, u, (size_t)NL*sizeof(float), hipMemcpyDeviceToDevice, stream);
    k_final<<<1, 64, 0, stream>>>(nrj, out + NL);
}

// Round 5
// 600.256 us; speedup vs baseline: 4.4565x; 1.1074x over previous
//
#include <hip/hip_runtime.h>

#define HH 256
#define WW 256
#define NPIX (HH*WW)
#define LL 16
#define NL (NPIX*LL)
#define PP 136
#define PP2 (PP*2)
#define NSET 8

typedef _Float16 half_t;
typedef __attribute__((ext_vector_type(8))) _Float16 half8;

// constants (double-evaluated, cast to float -- matches JAX weak-typed scalars)
static constexpr float SIGMAP_F = (float)((1.0/256.0)/(3.0+16.0)); // res/(3+l)
static constexpr float TAUU_F   = (float)((1.0/256.0)/6.0);        // res/6
static constexpr float TAU_F    = (float)(1.0/36.0);               // 1/(2+136/4)

__device__ __forceinline__ float clampf(float x, float lo, float hi){
    return fminf(fmaxf(x, lo), hi);
}

// ---------------- init: u/ubar = f broadcast; px/pt = 0; nrj = 0 -------------
__global__ __launch_bounds__(256) void k_init(const float* __restrict__ f,
    float* __restrict__ u, float* __restrict__ ubar,
    float* __restrict__ px, float* __restrict__ pt, float* __restrict__ nrj)
{
    int tid = blockIdx.x*256 + threadIdx.x;
    if (tid == 0) *nrj = 0.0f;
    if (tid >= NL) return;
    int n = tid >> 4;
    float fv = f[n];
    u[tid] = fv; ubar[tid] = fv;
    px[tid] = 0.0f; px[NL + tid] = 0.0f;
    pt[tid] = 0.0f;
}

// ---------------- prox: dual p update (per pixel,label) ----------------------
__global__ __launch_bounds__(256) void k_prox(const float* __restrict__ f,
    const float* __restrict__ ubar,
    float* __restrict__ px, float* __restrict__ pt,
    const half_t* __restrict__ msAll)   // 8 partial musums: [h][d][n][z]
{
    int tid = blockIdx.x*256 + threadIdx.x;
    if (tid >= NL) return;
    int z = tid & (LL-1);
    int n = tid >> 4;
    int i = n >> 8;
    int j = n & (WW-1);

    float ub = ubar[tid];
    float g0 = (i < HH-1) ? (ubar[tid + WW*LL] - ub) * 256.0f : 0.0f;
    float g1 = (j < WW-1) ? (ubar[tid + LL]    - ub) * 256.0f : 0.0f;
    float gt = (z < LL-1) ? (ubar[tid + 1]     - ub) * 16.0f  : 0.0f;

    float ms0 = 0.0f, ms1 = 0.0f;
    #pragma unroll
    for (int h2 = 0; h2 < NSET; ++h2) {
        ms0 += (float)msAll[(size_t)h2*2*NL + tid];
        ms1 += (float)msAll[(size_t)h2*2*NL + NL + tid];
    }

    float ux0 = px[tid]      + SIGMAP_F * (g0 + ms0);
    float ux1 = px[NL + tid] + SIGMAP_F * (g1 + ms1);
    float ut  = pt[tid]      + SIGMAP_F * gt;

    float klf = (float)(z + 1) * 0.0625f - f[n];
    float pen = 0.5f * klf * klf;            // lmbda = 0.5

    float n2 = ux0*ux0 + ux1*ux1;
    float B  = 0.25f * n2 - pen;
    bool mask = ut < B;

    float px0 = ux0, px1 = ux1, ptn = ut;
    if (mask) {
        float y    = ut + pen;
        float norm = sqrtf(n2);
        float a    = 0.5f * norm;
        float b    = (2.0f/3.0f) * (1.0f - 0.5f*y);
        float v;
        if (b < 0.0f) {
            float sb  = sqrtf(-b);
            float sb3 = sb*sb*sb;
            float dd  = (a - sb3)*(a + sb3);
            if (dd < 0.0f) {
                float ratio = clampf(a / sb3, -1.0f, 1.0f);
                v = 2.0f * sb * cosf(acosf(ratio) * (1.0f/3.0f));
            } else {
                float c = cbrtf(a + sqrtf(dd));
                v = (c == 0.0f) ? 0.0f : (c - b/c);
            }
        } else {
            float dd = a*a + b*b*b;          // >= 0
            float c  = cbrtf(a + sqrtf(dd));
            v = (c == 0.0f) ? 0.0f : (c - b/c);
        }
        if (norm == 0.0f) { px0 = 0.0f; px1 = 0.0f; }
        else              { float s = 2.0f*v/norm; px0 = s*ux0; px1 = s*ux1; }
        ptn = 0.25f*(px0*px0 + px1*px1) - pen;
    }
    px[tid] = px0; px[NL + tid] = px1; pt[tid] = ptn;
}

// ---------------- fused s/mu update + primal u update ------------------------
// 8-way row split: set H handles rows {H, 15-H} of the combo triangle
// (16-H + H+1 = 17 combos each, perfectly balanced, all indices static).
// Storage layout per set (chunk-vectorized for half8 access):
//   q = position in set's processing order (0..16); chunks {0..7},{8..15},{16}
//   elem offset = H*17*2*NPIX + 8c*2*NPIX + n*(2*G) + d*G + (q-8c), G=8 (or 1)
//   -> each thread's chunk is 8 contiguous fp16 = one 16B load/store.
// Partial musum per set (RS/C recurrence is valid on any row subset).
// snorm couples d=0/1 -> __shfl_xor(1) (lane pairs share n,h).
template<int H>
__device__ __forceinline__ void do_set(int d, int n,
    const float* __restrict__ p,
    half_t* __restrict__ sx, const half_t* __restrict__ muCur,
    half_t* __restrict__ muOld, float* __restrict__ RS, float* __restrict__ C)
{
    constexpr size_t setbase = (size_t)H * 17 * 2 * NPIX;
    const size_t vb   = setbase + (size_t)n*16 + (size_t)d*8;    // chunk0 (elems)
    const size_t vb1  = vb + (size_t)16*NPIX;                    // chunk1
    const size_t tail = setbase + (size_t)32*NPIX + (size_t)n*2 + (size_t)d;

    half8 sxv0 = *reinterpret_cast<const half8*>(&sx[vb]);
    half8 sxv1 = *reinterpret_cast<const half8*>(&sx[vb1]);
    half8 mCv0 = *reinterpret_cast<const half8*>(&muCur[vb]);
    half8 mCv1 = *reinterpret_cast<const half8*>(&muCur[vb1]);
    half8 mOv0 = *reinterpret_cast<const half8*>(&muOld[vb]);
    half8 mOv1 = *reinterpret_cast<const half8*>(&muOld[vb1]);
    float sxT = (float)sx[tail];
    float mCT = (float)muCur[tail];
    float mOT = (float)muOld[tail];

    half8 sxo0, sxo1, muo0, muo1;
    half_t sxoT = (half_t)0.0f, muoT = (half_t)0.0f;

    float tsum = 0.0f, rsA = 0.0f, rsB = 0.0f;
    #pragma unroll
    for (int q = 0; q < 17; ++q) {
        const int b = (q <= 15-H) ? H + q : q - 1;   // static under unroll
        float sxval, mCval, mOval;
        if (q < 8)       { sxval=(float)sxv0[q];   mCval=(float)mCv0[q];   mOval=(float)mOv0[q]; }
        else if (q < 16) { sxval=(float)sxv1[q-8]; mCval=(float)mCv1[q-8]; mOval=(float)mOv1[q-8]; }
        else             { sxval=sxT;              mCval=mCT;              mOval=mOT; }

        if (q == 0 || q == 16-H) tsum = 0.0f;        // row start
        tsum += p[b];

        // mubar = 2*muCur - muOld ; mx = sx - mubar (sigmas = 1)
        float mx = sxval - (2.0f*mCval - mOval);
        float mo = __shfl_xor(mx, 1);
        float snorm = sqrtf(mx*mx + mo*mo);
        if (snorm > 25.6f) mx *= 0.1f / snorm;       // nu*H ; nu/snorm
        float mn = mCval + TAU_F*(mx - tsum);

        if (q < 8)       { sxo0[q]   = (half_t)mx; muo0[q]   = (half_t)mn; }
        else if (q < 16) { sxo1[q-8] = (half_t)mx; muo1[q-8] = (half_t)mn; }
        else             { sxoT      = (half_t)mx; muoT      = (half_t)mn; }

        if (q <= 15-H) rsA += mn; else rsB += mn;
        C[b] += mn;
    }
    RS[H]    = rsA;
    RS[15-H] = rsB;

    *reinterpret_cast<half8*>(&sx[vb])     = sxo0;
    *reinterpret_cast<half8*>(&sx[vb1])    = sxo1;
    *reinterpret_cast<half8*>(&muOld[vb])  = muo0;
    *reinterpret_cast<half8*>(&muOld[vb1]) = muo1;
    sx[tail]    = sxoT;
    muOld[tail] = muoT;
}

__global__ __launch_bounds__(256) void k_smu_u(const float* __restrict__ px,
    const float* __restrict__ pt,
    half_t* __restrict__ sx,
    const half_t* __restrict__ muCur,   // mu_t      (read)
    half_t* __restrict__ muOld,         // mu_{t-1}  (read) -> mu_{t+1} (write)
    half_t* __restrict__ msAll,         // [h][d][n][z] fp16 partials
    float* __restrict__ u, float* __restrict__ ubar,
    float* __restrict__ nrj, int compute_nrj)
{
    __shared__ float wsum[4];
    int t = blockIdx.x*256 + threadIdx.x;   // [0, 16*NPIX)
    int d = t & 1;
    int n = (t >> 1) & (NPIX-1);
    int h = t >> 17;                        // 0..7, block-uniform

    // ---------------- phase A: s & mu ----------------
    float p[LL];
    {
        const float4* pxd = reinterpret_cast<const float4*>(px + (size_t)d*NL + (size_t)n*LL);
        #pragma unroll
        for (int q = 0; q < LL/4; ++q) {
            float4 a = pxd[q];
            p[4*q+0]=a.x; p[4*q+1]=a.y; p[4*q+2]=a.z; p[4*q+3]=a.w;
        }
    }

    float RS[LL], C[LL];
    #pragma unroll
    for (int q = 0; q < LL; ++q) { RS[q]=0.f; C[q]=0.f; }

    if      (h == 0) do_set<0>(d,n,p,sx,muCur,muOld,RS,C);
    else if (h == 1) do_set<1>(d,n,p,sx,muCur,muOld,RS,C);
    else if (h == 2) do_set<2>(d,n,p,sx,muCur,muOld,RS,C);
    else if (h == 3) do_set<3>(d,n,p,sx,muCur,muOld,RS,C);
    else if (h == 4) do_set<4>(d,n,p,sx,muCur,muOld,RS,C);
    else if (h == 5) do_set<5>(d,n,p,sx,muCur,muOld,RS,C);
    else if (h == 6) do_set<6>(d,n,p,sx,muCur,muOld,RS,C);
    else             do_set<7>(d,n,p,sx,muCur,muOld,RS,C);

    // partial musum over this row-subset:
    // ms[0]=RS[0]; ms[z+1]=ms[z]+RS[z+1]-C[z]   (RS zero for rows not in set)
    {
        half_t* msd = msAll + (size_t)h*2*NL + (size_t)d*NL + (size_t)n*LL;
        half8 m0, m1;
        float m = RS[0];
        m0[0] = (half_t)m;
        #pragma unroll
        for (int zq = 1; zq < LL; ++zq) {
            m += RS[zq] - C[zq-1];
            if (zq < 8) m0[zq] = (half_t)m; else m1[zq-8] = (half_t)m;
        }
        *reinterpret_cast<half8*>(msd)     = m0;
        *reinterpret_cast<half8*>(msd + 8) = m1;
    }

    // ---------------- phase B: primal u update (1 z per thread) --------------
    // independent of phase A (depends only on prox outputs) -- no sync needed
    {
        int tid = t;
        int z  = tid & (LL-1);
        int n2 = tid >> 4;
        int i2 = n2 >> 8;
        int j2 = n2 & (WW-1);

        float p0c = px[tid];
        float p1c = px[NL + tid];
        float d0 = ((i2 < HH-1) ? p0c : 0.0f) - ((i2 > 0) ? px[tid - WW*LL] : 0.0f);
        float d1 = ((j2 < WW-1) ? p1c : 0.0f) - ((j2 > 0) ? px[NL + tid - LL] : 0.0f);
        float ptc = pt[tid];
        float dt = ((z < LL-1) ? ptc : 0.0f) - ((z > 0) ? pt[tid - 1] : 0.0f);

        float uo = u[tid];
        float Dv = uo + TAUU_F * ((d0 + d1) * 256.0f + dt * 16.0f);
        float un = clampf(Dv, 0.0f, 1.0f);
        if (z == 0)     un = 1.0f;
        if (z == LL-1)  un = 0.0f;
        u[tid]    = un;
        ubar[tid] = 2.0f*un - uo;

        if (compute_nrj) {
            float v = fabsf(un - uo);
            #pragma unroll
            for (int off = 32; off > 0; off >>= 1) v += __shfl_down(v, off);
            int lane = threadIdx.x & 63, wv = threadIdx.x >> 6;
            if (lane == 0) wsum[wv] = v;
            __syncthreads();
            if (threadIdx.x == 0) {
                atomicAdd(nrj, wsum[0] + wsum[1] + wsum[2] + wsum[3]);
            }
        }
    }
}

// ---------------- tail scalars ----------------------------------------------
__global__ void k_final(const float* __restrict__ nrj, float* __restrict__ out_tail)
{
    if (threadIdx.x == 0) {
        float e = *nrj;
        out_tail[0] = e;
        out_tail[1] = e * (1.0f/1048576.0f);   // nrj / (H*W*1*l)
        out_tail[2] = 0.0f;
    }
}

extern "C" void kernel_launch(void* const* d_in, const int* in_sizes, int n_in,
                              void* d_out, int out_size, void* d_ws, size_t ws_size,
                              hipStream_t stream)
{
    const float* f = (const float*)d_in[0];
    float* out = (float*)d_out;

    char* w = (char*)d_ws;
    size_t off = 0;
    auto allocf = [&](size_t nfloats) {
        float* p = (float*)(w + off);
        off += nfloats * sizeof(float);
        return p;
    };
    auto alloch = [&](size_t nhalf) {
        half_t* p = (half_t*)(w + off);
        off += nhalf * sizeof(half_t);
        return p;
    };
    // fp16 block (memset together): sx, muA, muB (chunk-vectorized), msAll
    half_t* sx    = alloch((size_t)NPIX * PP2);     // 35.7 MB
    half_t* muA   = alloch((size_t)NPIX * PP2);     // 35.7 MB
    half_t* muB   = alloch((size_t)NPIX * PP2);     // 35.7 MB
    half_t* msAll = alloch((size_t)NSET * 2 * NL);  // 33.6 MB (8 partials)
    size_t half_bytes = off;
    float*  px    = allocf(2*(size_t)NL);           // 8.4 MB
    float*  pt    = allocf((size_t)NL);             // 4.2 MB
    float*  u     = allocf((size_t)NL);             // 4.2 MB
    float*  ubar  = allocf((size_t)NL);             // 4.2 MB
    float*  nrj   = allocf(64);
    (void)ws_size; (void)in_sizes; (void)n_in; (void)out_size;

    hipMemsetAsync(sx, 0, half_bytes, stream);
    k_init<<<NL/256, 256, 0, stream>>>(f, u, ubar, px, pt, nrj);

    half_t* mcur = muB;   // mu_t      (zeros initially)
    half_t* mold = muA;   // mu_{t-1}  (zeros initially)
    for (int it = 0; it < 10; ++it) {
        k_prox<<<NL/256, 256, 0, stream>>>(f, ubar, px, pt, msAll);
        k_smu_u<<<16*NPIX/256, 256, 0, stream>>>(px, pt, sx, mcur, mold, msAll,
                                                 u, ubar, nrj, it == 0 ? 1 : 0);
        { half_t* tmp = mcur; mcur = mold; mold = tmp; }  // mold now holds mu_{t+1}
    }

    hipMemcpyAsync(out, u, (size_t)NL*sizeof(float), hipMemcpyDeviceToDevice, stream);
    k_final<<<1, 64, 0, stream>>>(nrj, out + NL);
}